// Round 1
// 2215.728 us; speedup vs baseline: 1.3487x; 1.3487x over previous
//
#include <hip/hip_runtime.h>
#include <math.h>

#define TT 512
#define BB 128
#define II 256
#define HH 512
#define BH (BB*HH)

#define NBLK 256
#define NTHR 256

#define FLAG_OFF 0           // 8 clusters x 128 wave-flags x 16B = 16384
#define XCC_OFF  16384       // 8 clusters x 32 x 4B = 1024
#define HBUF_OFF 20480
#define HBUF_PLANE 16384     // one plane: 16 rows x 512 cols bf16

typedef __bf16 bf16x8 __attribute__((ext_vector_type(8)));
typedef float  f32x4  __attribute__((ext_vector_type(4)));
typedef unsigned long long u64;

__device__ __forceinline__ float sigf(float v)   { return 1.f / (1.f + __expf(-v)); }
__device__ __forceinline__ float tanhf_(float v) { return 2.f / (1.f + __expf(-2.f * v)) - 1.f; }

__device__ __forceinline__ void split8(const float* p, bf16x8& h8, bf16x8& l8) {
    f32x4 a = *(const f32x4*)p;
    f32x4 b = *(const f32x4*)(p + 4);
    float v[8] = {a[0], a[1], a[2], a[3], b[0], b[1], b[2], b[3]};
    #pragma unroll
    for (int e = 0; e < 8; ++e) {
        __bf16 hh = (__bf16)v[e];
        h8[e] = hh;
        l8[e] = (__bf16)(v[e] - (float)hh);
    }
}

__device__ __forceinline__ void split8r(f32x4 a, f32x4 b, bf16x8& h8, bf16x8& l8) {
    float v[8] = {a[0], a[1], a[2], a[3], b[0], b[1], b[2], b[3]};
    #pragma unroll
    for (int e = 0; e < 8; ++e) {
        __bf16 hh = (__bf16)v[e];
        h8[e] = hh;
        l8[e] = (__bf16)(v[e] - (float)hh);
    }
}

// 16B fragment load from the h-planes: two 8B relaxed agent-scope atomic loads
// -> global_load_dwordx2 with sc0 (L1 bypass) -> always reads the XCD-L2 copy.
__device__ __forceinline__ bf16x8 load_frag_sc0(const __bf16* p) {
    union { u64 q[2]; bf16x8 v; } u;
    const u64* qp = (const u64*)p;
    u.q[0] = __hip_atomic_load(qp,     __ATOMIC_RELAXED, __HIP_MEMORY_SCOPE_AGENT);
    u.q[1] = __hip_atomic_load(qp + 1, __ATOMIC_RELAXED, __HIP_MEMORY_SCOPE_AGENT);
    return u.v;
}

// Barriers that do NOT drain vmcnt: keep x-prefetch loads and out-stores in
// flight across steps. gbuf (LDS) hazards only need lgkmcnt / arrival.
__device__ __forceinline__ void barrier_lgkm() {
    asm volatile("s_waitcnt lgkmcnt(0)" ::: "memory");
    __builtin_amdgcn_s_barrier();
    asm volatile("" ::: "memory");
}
__device__ __forceinline__ void barrier_bare() {
    asm volatile("" ::: "memory");
    __builtin_amdgcn_s_barrier();
    asm volatile("" ::: "memory");
}

__global__ __launch_bounds__(NTHR, 1) void lstm_mfma4(
    const float* __restrict__ x,
    const float* __restrict__ Wf, const float* __restrict__ bf_,
    const float* __restrict__ Wu, const float* __restrict__ bu_,
    const float* __restrict__ Wc, const float* __restrict__ bc_,
    const float* __restrict__ Wo, const float* __restrict__ bo_,
    float* __restrict__ out, char* __restrict__ ws)
{
    __shared__ __attribute__((aligned(16))) float gbuf[16][64][4];   // [g*4+wv][lane][4]

    const int tid  = threadIdx.x;
    const int wv   = tid >> 6;
    const int lane = tid & 63;
    const int cluster = blockIdx.x & 7;       // same-XCD under %8 round-robin
    const int jblk    = blockIdx.x >> 3;      // 0..31 within cluster
    const int j0 = jblk * 16;
    const int b0 = cluster * 16;
    const int n_ = lane & 15, quad = lane >> 4, k0 = quad * 8;

    // epilogue mapping: one output element per thread
    const int R  = tid >> 4;                  // 0..15 batch row within tile
    const int C  = tid & 15;                  // 0..15 output col within tile
    const int gl = ((R >> 2) << 4) | C;       // producer lane in gbuf
    const int ge = R & 3;                     // producer element

    unsigned* flags = (unsigned*)(ws + FLAG_OFF) + cluster * 512;   // 128 wave-flags, 16B apart
    unsigned* xccp  = (unsigned*)(ws + XCC_OFF)  + cluster * 32;

    // ---- XCD handshake: publish my XCC_ID, check the whole cluster matches ----
    const unsigned myxcc = __builtin_amdgcn_s_getreg((3 << 11) | 20);  // hwreg(XCC_ID,0,4)
    if (tid == 0)
        __hip_atomic_store(xccp + jblk, 0x100u | myxcc,
                           __ATOMIC_RELAXED, __HIP_MEMORY_SCOPE_AGENT);

    const float* Ws[4] = {Wf, Wu, Wc, Wo};
    const float* Bs[4] = {bf_, bu_, bc_, bo_};

    // W fragments in registers. Wave wv owns z-K: x[wv*64,+64) and h[wv*128,+128)
    bf16x8 bxh[4][2], bxl[4][2], bhh[4][4], bhl[4][4];
    #pragma unroll
    for (int g = 0; g < 4; ++g) {
        const float* wr = Ws[g] + (size_t)(j0 + n_) * 768;
        #pragma unroll
        for (int kt = 0; kt < 2; ++kt)
            split8(wr + wv * 64 + kt * 32 + k0, bxh[g][kt], bxl[g][kt]);
        #pragma unroll
        for (int kt = 0; kt < 4; ++kt)
            split8(wr + 256 + wv * 128 + kt * 32 + k0, bhh[g][kt], bhl[g][kt]);
    }
    float biasg[4];
    #pragma unroll
    for (int g = 0; g < 4; ++g) biasg[g] = Bs[g][j0 + C];

    // x goes straight from global to MFMA fragments: per-lane source pointer.
    // Lane needs cols [wv*64 + kt*32 + k0, +8) of row b0+n_ -> 4 dwordx4 loads.
    const float* xb = x + (size_t)(b0 + n_) * (TT * II) + wv * 64 + k0;
    f32x4 xr0 = *(const f32x4*)(xb);          // t=0, kt=0
    f32x4 xr1 = *(const f32x4*)(xb + 4);
    f32x4 xr2 = *(const f32x4*)(xb + 32);     // t=0, kt=1
    f32x4 xr3 = *(const f32x4*)(xb + 36);

    // finish handshake (overlapped with W staging + x0 load above)
    bool fast;
    {
        const unsigned mine = 0x100u | myxcc;
        while (true) {
            unsigned w = mine;
            if (lane < 32)
                w = __hip_atomic_load(xccp + lane, __ATOMIC_RELAXED, __HIP_MEMORY_SCOPE_AGENT);
            if (__all((int)(w >= 0x100u))) {
                fast = (bool)__all((int)(w == mine));
                break;
            }
            __builtin_amdgcn_s_sleep(2);
        }
    }
    __syncthreads();

    float cth = 0.f, hth = 0.f;   // per-thread c,h state for (b0+R, j0+C)

    for (int t = 0; t < TT; ++t) {
        f32x4 acc[4][3];
        #pragma unroll
        for (int g = 0; g < 4; ++g)
            #pragma unroll
            for (int s = 0; s < 3; ++s)
                acc[g][s] = (f32x4){0.f, 0.f, 0.f, 0.f};

        // ---- phase A: x-contribution from registers (prefetched last step) ----
        bf16x8 axh0, axl0, axh1, axl1;
        split8r(xr0, xr1, axh0, axl0);
        split8r(xr2, xr3, axh1, axl1);

        if (t + 1 < TT) {   // prefetch x_{t+1}; retires under this whole step
            const float* p = xb + (size_t)(t + 1) * II;
            xr0 = *(const f32x4*)(p);
            xr1 = *(const f32x4*)(p + 4);
            xr2 = *(const f32x4*)(p + 32);
            xr3 = *(const f32x4*)(p + 36);
        }

        #pragma unroll
        for (int g = 0; g < 4; ++g) {
            acc[g][0] = __builtin_amdgcn_mfma_f32_16x16x32_bf16(axh0, bxh[g][0], acc[g][0], 0, 0, 0);
            acc[g][1] = __builtin_amdgcn_mfma_f32_16x16x32_bf16(axh0, bxl[g][0], acc[g][1], 0, 0, 0);
            acc[g][2] = __builtin_amdgcn_mfma_f32_16x16x32_bf16(axl0, bxh[g][0], acc[g][2], 0, 0, 0);
        }
        #pragma unroll
        for (int g = 0; g < 4; ++g) {
            acc[g][0] = __builtin_amdgcn_mfma_f32_16x16x32_bf16(axh1, bxh[g][1], acc[g][0], 0, 0, 0);
            acc[g][1] = __builtin_amdgcn_mfma_f32_16x16x32_bf16(axh1, bxl[g][1], acc[g][1], 0, 0, 0);
            acc[g][2] = __builtin_amdgcn_mfma_f32_16x16x32_bf16(axl1, bxh[g][1], acc[g][2], 0, 0, 0);
        }

        // ---- per-wave wait for this wave's 8 blocks x 4 producer waves ----
        if (t > 0) {
            const unsigned tgt = (unsigned)t;
            const unsigned* fp = flags + ((wv * 8 + (lane >> 2)) * 4 + (lane & 3)) * 4;
            while (true) {
                unsigned v = tgt;
                if (lane < 32)
                    v = __hip_atomic_load(fp, __ATOMIC_RELAXED, __HIP_MEMORY_SCOPE_AGENT);
                if (__all((int)(v >= tgt))) break;
                __builtin_amdgcn_s_sleep(1);
            }
            if (!fast) __builtin_amdgcn_fence(__ATOMIC_ACQUIRE, "agent");
            else       asm volatile("" ::: "memory");   // compiler barrier only

            const size_t base = HBUF_OFF + (size_t)((((t - 1) & 1) * 8 + cluster) * 2) * HBUF_PLANE;
            const __bf16* hp = (const __bf16*)(ws + base);
            const __bf16* lp = (const __bf16*)(ws + base + HBUF_PLANE);
            const int off = n_ * HH + wv * 128 + k0;
            bf16x8 ah[4], al[4];
            #pragma unroll
            for (int kt = 0; kt < 4; ++kt) {            // batch-issue all 8 L2 loads
                ah[kt] = load_frag_sc0(hp + off + kt * 32);
                al[kt] = load_frag_sc0(lp + off + kt * 32);
            }
            #pragma unroll
            for (int kt = 0; kt < 4; ++kt)
                #pragma unroll
                for (int g = 0; g < 4; ++g) {
                    acc[g][0] = __builtin_amdgcn_mfma_f32_16x16x32_bf16(ah[kt], bhh[g][kt], acc[g][0], 0, 0, 0);
                    acc[g][1] = __builtin_amdgcn_mfma_f32_16x16x32_bf16(ah[kt], bhl[g][kt], acc[g][1], 0, 0, 0);
                    acc[g][2] = __builtin_amdgcn_mfma_f32_16x16x32_bf16(al[kt], bhh[g][kt], acc[g][2], 0, 0, 0);
                }
        }

        // ---- cross-wave K reduction through LDS ----
        #pragma unroll
        for (int g = 0; g < 4; ++g) {
            f32x4 pre = acc[g][0] + acc[g][1] + acc[g][2];
            *(f32x4*)&gbuf[g * 4 + wv][lane][0] = pre;
        }
        barrier_lgkm();

        // ---- all-wave epilogue: one output element per thread ----
        float sg[4];
        #pragma unroll
        for (int g = 0; g < 4; ++g) {
            float a0 = gbuf[g * 4 + 0][gl][ge];
            float a1 = gbuf[g * 4 + 1][gl][ge];
            float a2 = gbuf[g * 4 + 2][gl][ge];
            float a3 = gbuf[g * 4 + 3][gl][ge];
            sg[g] = (a0 + a1) + (a2 + a3) + biasg[g];
        }
        float fg = sigf(sg[0]);
        float ug = sigf(sg[1]);
        float gg = tanhf_(sg[2]);
        float og = sigf(sg[3]);
        cth = fg * cth + ug * gg;
        float hv = og * tanhf_(cth);
        hth = hv;

        if (t < TT - 1) {
            const size_t dbase = HBUF_OFF + (size_t)(((t & 1) * 8 + cluster) * 2) * HBUF_PLANE;
            __bf16* dh = (__bf16*)(ws + dbase);
            __bf16* dl = (__bf16*)(ws + dbase + HBUF_PLANE);
            __bf16 hh = (__bf16)hv;
            dh[R * HH + j0 + C] = hh;
            dl[R * HH + j0 + C] = (__bf16)(hv - (float)hh);
            // publish this wave's 4 rows: drain own stores to L2, then wave-flag.
            asm volatile("s_waitcnt vmcnt(0)" ::: "memory");
            if (!fast) __builtin_amdgcn_fence(__ATOMIC_RELEASE, "agent");
            if (lane == 0)
                __hip_atomic_store(flags + (jblk * 4 + wv) * 4, (unsigned)(t + 1),
                                   __ATOMIC_RELAXED, __HIP_MEMORY_SCOPE_AGENT);
        }
        // fp32 output store AFTER the flag: off the serial path, never drained
        // at barriers (bare s_barrier), retires in the background.
        out[(size_t)t * BH + (size_t)(b0 + R) * HH + j0 + C] = hv;
        barrier_bare();
    }

    out[(size_t)TT * BH +      (size_t)(b0 + R) * HH + j0 + C] = hth;
    out[(size_t)TT * BH + BH + (size_t)(b0 + R) * HH + j0 + C] = cth;
}

extern "C" void kernel_launch(void* const* d_in, const int* in_sizes, int n_in,
                              void* d_out, int out_size, void* d_ws, size_t ws_size,
                              hipStream_t stream) {
    (void)in_sizes; (void)n_in; (void)out_size; (void)ws_size;
    const float* x  = (const float*)d_in[0];
    const float* Wf = (const float*)d_in[1];
    const float* bf = (const float*)d_in[2];
    const float* Wu = (const float*)d_in[3];
    const float* bu = (const float*)d_in[4];
    const float* Wc = (const float*)d_in[5];
    const float* bc = (const float*)d_in[6];
    const float* Wo = (const float*)d_in[7];
    const float* bo = (const float*)d_in[8];

    hipMemsetAsync(d_ws, 0, HBUF_OFF, stream);   // flags + xcc handshake area
    lstm_mfma4<<<dim3(NBLK), dim3(NTHR), 0, stream>>>(
        x, Wf, bf, Wu, bu, Wc, bc, Wo, bo, (float*)d_out, (char*)d_ws);
}